// Round 3
// baseline (5807.785 us; speedup 1.0000x reference)
//
#include <hip/hip_runtime.h>
#include <hip/hip_bf16.h>

#define NRAYS 8192
#define SAMP  128
#define HID   64
#define DVD   27
#define NFEAT 15

// sin(x), cos(x) via hardware v_sin/v_cos (take REVOLUTIONS; explicit fract
// reduction keeps inside the valid HW domain).
static __device__ __forceinline__ float sin_fast(float x) {
    float r = x * 0.15915494309189535f;   // x / (2*pi)
    r = r - floorf(r);
    return __builtin_amdgcn_sinf(r);
}
static __device__ __forceinline__ float cos_fast(float x) {
    float r = x * 0.15915494309189535f;
    r = r - floorf(r);
    return __builtin_amdgcn_cosf(r);
}

// ---------------------------------------------------------------------------
// Kernel 1: dt = mean(tmax - tmin) / S   (global scalar -> d_ws[0])
// ---------------------------------------------------------------------------
__global__ void dt_kernel(const float* __restrict__ tmin,
                          const float* __restrict__ tmax,
                          float* __restrict__ dt_out) {
    __shared__ float red[256];
    float s = 0.0f;
    for (int i = threadIdx.x; i < NRAYS; i += 256)
        s += tmax[i] - tmin[i];
    red[threadIdx.x] = s;
    __syncthreads();
    for (int off = 128; off > 0; off >>= 1) {
        if (threadIdx.x < off) red[threadIdx.x] += red[threadIdx.x + off];
        __syncthreads();
    }
    if (threadIdx.x == 0)
        dt_out[0] = red[0] / (float)NRAYS / (float)SAMP;
}

// ---------------------------------------------------------------------------
// Kernel 2: one wave per ray; each lane handles samples 2*lane, 2*lane+1.
// Weights staged fp32 in LDS, read as wave-broadcasts (conflict-free).
// ---------------------------------------------------------------------------
__global__ void __launch_bounds__(256)
march_kernel(const float* __restrict__ orig,
             const float* __restrict__ dirs,
             const float* __restrict__ tmin,
             const float* __restrict__ tmax,
             const float* __restrict__ W1,
             const float* __restrict__ b1,
             const float* __restrict__ W2,
             const float* __restrict__ b2,
             const float* __restrict__ V1,
             const float* __restrict__ c1,
             const float* __restrict__ V2,
             const float* __restrict__ c2,
             const float* __restrict__ dtp,
             float* __restrict__ out) {
    __shared__ float sW1[63 * HID];   // 4032
    __shared__ float sb1[HID];
    __shared__ float sW2[HID * 16];   // 1024
    __shared__ float sb2[16];
    __shared__ float sV1[42 * HID];   // 2688
    __shared__ float sc1[HID];
    __shared__ float sV2[HID * 3];    // 192
    __shared__ float sc2[3];
    __shared__ float sVde[4 * DVD];   // per-wave view-dir encoding

    const int tid = threadIdx.x;
    for (int i = tid; i < 63 * HID; i += 256) sW1[i] = W1[i];
    for (int i = tid; i < HID;      i += 256) sb1[i] = b1[i];
    for (int i = tid; i < HID * 16; i += 256) sW2[i] = W2[i];
    for (int i = tid; i < 16;       i += 256) sb2[i] = b2[i];
    for (int i = tid; i < 42 * HID; i += 256) sV1[i] = V1[i];
    for (int i = tid; i < HID;      i += 256) sc1[i] = c1[i];
    for (int i = tid; i < HID * 3;  i += 256) sV2[i] = V2[i];
    for (int i = tid; i < 3;        i += 256) sc2[i] = c2[i];

    const int lane = tid & 63;
    const int wave = tid >> 6;
    const int ray  = blockIdx.x * 4 + wave;

    const float ox = orig[ray * 3 + 0];
    const float oy = orig[ray * 3 + 1];
    const float oz = orig[ray * 3 + 2];
    const float dx = dirs[ray * 3 + 0];
    const float dy = dirs[ray * 3 + 1];
    const float dz = dirs[ray * 3 + 2];
    const float t0 = tmin[ray];
    const float trange = tmax[ray] - t0;
    const float dt = dtp[0];

    // view-dir encoding -> per-wave LDS (element `lane` computed by lanes 0..26)
    {
        const float nrm = sqrtf(dx * dx + dy * dy + dz * dz);
        const float inv = 1.0f / (nrm + 1e-8f);
        const float vx = dx * inv, vy = dy * inv, vz = dz * inv;
        if (lane < DVD) {
            float val;
            if (lane < 3) {
                val = (lane == 0) ? vx : ((lane == 1) ? vy : vz);
            } else {
                const int q = lane - 3;
                const int b = q / 6;
                const int r = q - 6 * b;
                const bool isSin = (r < 3);
                const int d = isSin ? r : (r - 3);
                const float comp = (d == 0) ? vx : ((d == 1) ? vy : vz);
                const float a = (float)(1 << b) * comp;
                val = isSin ? sin_fast(a) : cos_fast(a);
            }
            sVde[wave * DVD + lane] = val;
        }
    }
    __syncthreads();

    float om[2], alp[2], rgbv[2][3];

    #pragma unroll
    for (int ss = 0; ss < 2; ss++) {
        const int s = lane * 2 + ss;
        const float u = (float)s * (1.0f / (float)(SAMP - 1));
        const float t = t0 + u * trange;
        const float px = ox + dx * t;
        const float py = oy + dy * t;
        const float pz = oz + dz * t;

        // ---- h = relu(enc @ W1 + b1) ----
        float h[HID];
        #pragma unroll
        for (int j = 0; j < HID; j++) h[j] = sb1[j];
        // identity rows 0..2
        {
            #pragma unroll
            for (int j = 0; j < HID; j++) h[j] += px * sW1[0 * HID + j];
            #pragma unroll
            for (int j = 0; j < HID; j++) h[j] += py * sW1[1 * HID + j];
            #pragma unroll
            for (int j = 0; j < HID; j++) h[j] += pz * sW1[2 * HID + j];
        }
        // band rows (rolled over bands; LDS offsets dynamic, reg indices static)
        for (int b = 0; b < 10; b++) {
            const float f = (float)(1 << b);
            #pragma unroll
            for (int d = 0; d < 3; d++) {
                const float a = f * ((d == 0) ? px : ((d == 1) ? py : pz));
                const float sv = sin_fast(a);
                const float cv = cos_fast(a);
                const int rs = (3 + 6 * b + d) * HID;
                const int rc = (3 + 6 * b + 3 + d) * HID;
                #pragma unroll
                for (int j = 0; j < HID; j++)
                    h[j] += sv * sW1[rs + j] + cv * sW1[rc + j];
            }
        }

        // ---- out = relu(h) @ W2 + b2  (fused into relu pass) ----
        float o[16];
        #pragma unroll
        for (int j = 0; j < 16; j++) o[j] = sb2[j];
        #pragma unroll
        for (int k = 0; k < HID; k++) {
            const float hv = fmaxf(h[k], 0.0f);
            #pragma unroll
            for (int j = 0; j < 16; j++) o[j] += hv * sW2[k * 16 + j];
        }
        const float sigma = fmaxf(o[0], 0.0f);

        // ---- g = relu([feat, vd_enc] @ V1 + c1) ----
        float g[HID];
        #pragma unroll
        for (int j = 0; j < HID; j++) g[j] = sc1[j];
        #pragma unroll
        for (int k = 0; k < NFEAT; k++) {
            const float e = o[1 + k];
            #pragma unroll
            for (int j = 0; j < HID; j++) g[j] += e * sV1[k * HID + j];
        }
        for (int k = 0; k < DVD; k++) {   // rolled: e comes from LDS
            const float e = sVde[wave * DVD + k];
            #pragma unroll
            for (int j = 0; j < HID; j++) g[j] += e * sV1[(NFEAT + k) * HID + j];
        }

        // ---- rgb = sigmoid(relu(g) @ V2 + c2)  (fused into relu pass) ----
        float r0 = sc2[0], r1 = sc2[1], r2 = sc2[2];
        #pragma unroll
        for (int k = 0; k < HID; k++) {
            const float gv = fmaxf(g[k], 0.0f);
            r0 += gv * sV2[k * 3 + 0];
            r1 += gv * sV2[k * 3 + 1];
            r2 += gv * sV2[k * 3 + 2];
        }
        rgbv[ss][0] = 1.0f / (1.0f + __expf(-r0));
        rgbv[ss][1] = 1.0f / (1.0f + __expf(-r1));
        rgbv[ss][2] = 1.0f / (1.0f + __expf(-r2));
        alp[ss] = 1.0f - __expf(-sigma * dt);
        om[ss]  = 1.0f - alp[ss];
    }

    // ---- exclusive multiplicative scan across the wave ----
    const float lp = om[0] * om[1];
    float inc = lp;
    #pragma unroll
    for (int off = 1; off < 64; off <<= 1) {
        const float q = __shfl_up(inc, off, 64);
        if (lane >= off) inc *= q;
    }
    float Texc = __shfl_up(inc, 1, 64);
    if (lane == 0) Texc = 1.0f;

    const float T0 = Texc;
    const float T1 = Texc * om[0];
    const float a0 = (T0 > 1e-4f) ? 1.0f : 0.0f;
    const float a1 = (T1 > 1e-4f) ? 1.0f : 0.0f;
    const float w0 = T0 * alp[0] * a0;
    const float w1 = T1 * alp[1] * a1;

    float cr = w0 * rgbv[0][0] + w1 * rgbv[1][0];
    float cg = w0 * rgbv[0][1] + w1 * rgbv[1][1];
    float cb = w0 * rgbv[0][2] + w1 * rgbv[1][2];
    float tp = (a0 > 0.0f ? om[0] : 1.0f) * (a1 > 0.0f ? om[1] : 1.0f);

    #pragma unroll
    for (int off = 32; off > 0; off >>= 1) {
        cr += __shfl_xor(cr, off, 64);
        cg += __shfl_xor(cg, off, 64);
        cb += __shfl_xor(cb, off, 64);
        tp *= __shfl_xor(tp, off, 64);
    }

    if (lane == 0) {
        out[ray * 3 + 0] = cr;
        out[ray * 3 + 1] = cg;
        out[ray * 3 + 2] = cb;
        out[NRAYS * 3 + ray] = tp;
    }
}

extern "C" void kernel_launch(void* const* d_in, const int* in_sizes, int n_in,
                              void* d_out, int out_size, void* d_ws, size_t ws_size,
                              hipStream_t stream) {
    const float* orig = (const float*)d_in[0];
    const float* dirs = (const float*)d_in[1];
    const float* tmin = (const float*)d_in[2];
    const float* tmax = (const float*)d_in[3];
    const float* W1   = (const float*)d_in[4];
    const float* b1   = (const float*)d_in[5];
    const float* W2   = (const float*)d_in[6];
    const float* b2   = (const float*)d_in[7];
    const float* V1   = (const float*)d_in[8];
    const float* c1   = (const float*)d_in[9];
    const float* V2   = (const float*)d_in[10];
    const float* c2   = (const float*)d_in[11];
    float* dtp = (float*)d_ws;

    dt_kernel<<<1, 256, 0, stream>>>(tmin, tmax, dtp);
    march_kernel<<<NRAYS / 4, 256, 0, stream>>>(orig, dirs, tmin, tmax,
                                                W1, b1, W2, b2, V1, c1, V2, c2,
                                                dtp, (float*)d_out);
}

// Round 4
// 5290.352 us; speedup vs baseline: 1.0978x; 1.0978x over previous
//
#include <hip/hip_runtime.h>
#include <hip/hip_bf16.h>

#define NRAYS 8192
#define SAMP  128
#define HID   64
#define DVD   27
#define NFEAT 15

// sin(x), cos(x) via hardware v_sin/v_cos (take REVOLUTIONS; explicit fract
// reduction keeps inside the valid HW domain).
static __device__ __forceinline__ float sin_fast(float x) {
    float r = x * 0.15915494309189535f;   // x / (2*pi)
    r = r - floorf(r);
    return __builtin_amdgcn_sinf(r);
}
static __device__ __forceinline__ float cos_fast(float x) {
    float r = x * 0.15915494309189535f;
    r = r - floorf(r);
    return __builtin_amdgcn_cosf(r);
}

// ---------------------------------------------------------------------------
// Kernel 1: dt = mean(tmax - tmin) / S   (global scalar -> d_ws[0])
// ---------------------------------------------------------------------------
__global__ void dt_kernel(const float* __restrict__ tmin,
                          const float* __restrict__ tmax,
                          float* __restrict__ dt_out) {
    __shared__ float red[256];
    float s = 0.0f;
    for (int i = threadIdx.x; i < NRAYS; i += 256)
        s += tmax[i] - tmin[i];
    red[threadIdx.x] = s;
    __syncthreads();
    for (int off = 128; off > 0; off >>= 1) {
        if (threadIdx.x < off) red[threadIdx.x] += red[threadIdx.x + off];
        __syncthreads();
    }
    if (threadIdx.x == 0)
        dt_out[0] = red[0] / (float)NRAYS / (float)SAMP;
}

// ---------------------------------------------------------------------------
// Kernel 2: one wave per ray; each lane handles samples 2*lane, 2*lane+1,
// processed strictly sequentially (unroll 1) so only ONE h[64]/g[64] is live
// at a time -> no scratch spill. Weights staged fp32 in LDS, broadcast reads.
// ---------------------------------------------------------------------------
__global__ void __launch_bounds__(256)
march_kernel(const float* __restrict__ orig,
             const float* __restrict__ dirs,
             const float* __restrict__ tmin,
             const float* __restrict__ tmax,
             const float* __restrict__ W1,
             const float* __restrict__ b1,
             const float* __restrict__ W2,
             const float* __restrict__ b2,
             const float* __restrict__ V1,
             const float* __restrict__ c1,
             const float* __restrict__ V2,
             const float* __restrict__ c2,
             const float* __restrict__ dtp,
             float* __restrict__ out) {
    __shared__ float sW1[63 * HID];   // 4032
    __shared__ float sb1[HID];
    __shared__ float sW2[HID * 16];   // 1024
    __shared__ float sb2[16];
    __shared__ float sV1[42 * HID];   // 2688
    __shared__ float sc1[HID];
    __shared__ float sV2[HID * 3];    // 192
    __shared__ float sc2[3];
    __shared__ float sVde[4 * DVD];   // per-wave view-dir encoding

    const int tid = threadIdx.x;
    for (int i = tid; i < 63 * HID; i += 256) sW1[i] = W1[i];
    for (int i = tid; i < HID;      i += 256) sb1[i] = b1[i];
    for (int i = tid; i < HID * 16; i += 256) sW2[i] = W2[i];
    for (int i = tid; i < 16;       i += 256) sb2[i] = b2[i];
    for (int i = tid; i < 42 * HID; i += 256) sV1[i] = V1[i];
    for (int i = tid; i < HID;      i += 256) sc1[i] = c1[i];
    for (int i = tid; i < HID * 3;  i += 256) sV2[i] = V2[i];
    for (int i = tid; i < 3;        i += 256) sc2[i] = c2[i];

    const int lane = tid & 63;
    const int wave = tid >> 6;
    const int ray  = blockIdx.x * 4 + wave;

    const float ox = orig[ray * 3 + 0];
    const float oy = orig[ray * 3 + 1];
    const float oz = orig[ray * 3 + 2];
    const float dx = dirs[ray * 3 + 0];
    const float dy = dirs[ray * 3 + 1];
    const float dz = dirs[ray * 3 + 2];
    const float t0 = tmin[ray];
    const float trange = tmax[ray] - t0;
    const float dt = dtp[0];

    // view-dir encoding -> per-wave LDS (element `lane` computed by lanes 0..26)
    {
        const float nrm = sqrtf(dx * dx + dy * dy + dz * dz);
        const float inv = 1.0f / (nrm + 1e-8f);
        const float vx = dx * inv, vy = dy * inv, vz = dz * inv;
        if (lane < DVD) {
            float val;
            if (lane < 3) {
                val = (lane == 0) ? vx : ((lane == 1) ? vy : vz);
            } else {
                const int q = lane - 3;
                const int b = q / 6;
                const int r = q - 6 * b;
                const bool isSin = (r < 3);
                const int d = isSin ? r : (r - 3);
                const float comp = (d == 0) ? vx : ((d == 1) ? vy : vz);
                const float a = (float)(1 << b) * comp;
                val = isSin ? sin_fast(a) : cos_fast(a);
            }
            sVde[wave * DVD + lane] = val;
        }
    }
    __syncthreads();

    // per-sample results, named scalars (NO dynamically-indexed arrays)
    float om0 = 1.0f, om1 = 1.0f, al0 = 0.0f, al1 = 0.0f;
    float rr0 = 0.0f, rg0 = 0.0f, rb0 = 0.0f;
    float rr1 = 0.0f, rg1 = 0.0f, rb1 = 0.0f;

    #pragma unroll 1
    for (int ss = 0; ss < 2; ss++) {
        const int s = lane * 2 + ss;
        const float u = (float)s * (1.0f / (float)(SAMP - 1));
        const float t = t0 + u * trange;
        const float px = ox + dx * t;
        const float py = oy + dy * t;
        const float pz = oz + dz * t;

        // ---- h = relu(enc @ W1 + b1) ----
        float h[HID];
        #pragma unroll
        for (int j = 0; j < HID; j++) h[j] = sb1[j];
        {
            #pragma unroll
            for (int j = 0; j < HID; j++) h[j] += px * sW1[0 * HID + j];
            #pragma unroll
            for (int j = 0; j < HID; j++) h[j] += py * sW1[1 * HID + j];
            #pragma unroll
            for (int j = 0; j < HID; j++) h[j] += pz * sW1[2 * HID + j];
        }
        // band rows: keep ROLLED (code size + regs); LDS offsets dynamic,
        // register indices static.
        #pragma unroll 1
        for (int b = 0; b < 10; b++) {
            const float f = (float)(1 << b);
            #pragma unroll 1
            for (int d = 0; d < 3; d++) {
                const float a = f * ((d == 0) ? px : ((d == 1) ? py : pz));
                const float sv = sin_fast(a);
                const float cv = cos_fast(a);
                const int rs = (3 + 6 * b + d) * HID;
                const int rc = (3 + 6 * b + 3 + d) * HID;
                #pragma unroll
                for (int j = 0; j < HID; j++)
                    h[j] += sv * sW1[rs + j] + cv * sW1[rc + j];
            }
        }

        // ---- o = relu(h) @ W2 + b2 ----
        float o[16];
        #pragma unroll
        for (int j = 0; j < 16; j++) o[j] = sb2[j];
        #pragma unroll
        for (int k = 0; k < HID; k++) {
            const float hv = fmaxf(h[k], 0.0f);
            #pragma unroll
            for (int j = 0; j < 16; j++) o[j] += hv * sW2[k * 16 + j];
        }
        const float sigma = fmaxf(o[0], 0.0f);

        // ---- g = relu([feat, vd_enc] @ V1 + c1) ----
        float g[HID];
        #pragma unroll
        for (int j = 0; j < HID; j++) g[j] = sc1[j];
        #pragma unroll
        for (int k = 0; k < NFEAT; k++) {
            const float e = o[1 + k];
            #pragma unroll
            for (int j = 0; j < HID; j++) g[j] += e * sV1[k * HID + j];
        }
        #pragma unroll 1
        for (int k = 0; k < DVD; k++) {   // rolled: e broadcast from LDS
            const float e = sVde[wave * DVD + k];
            #pragma unroll
            for (int j = 0; j < HID; j++) g[j] += e * sV1[(NFEAT + k) * HID + j];
        }

        // ---- rgb = sigmoid(relu(g) @ V2 + c2) ----
        float r0 = sc2[0], r1 = sc2[1], r2 = sc2[2];
        #pragma unroll
        for (int k = 0; k < HID; k++) {
            const float gv = fmaxf(g[k], 0.0f);
            r0 += gv * sV2[k * 3 + 0];
            r1 += gv * sV2[k * 3 + 1];
            r2 += gv * sV2[k * 3 + 2];
        }
        const float sr = 1.0f / (1.0f + __expf(-r0));
        const float sg = 1.0f / (1.0f + __expf(-r1));
        const float sb = 1.0f / (1.0f + __expf(-r2));
        const float alpha = 1.0f - __expf(-sigma * dt);
        const float omv = 1.0f - alpha;

        if (ss == 0) { om0 = omv; al0 = alpha; rr0 = sr; rg0 = sg; rb0 = sb; }
        else         { om1 = omv; al1 = alpha; rr1 = sr; rg1 = sg; rb1 = sb; }
    }

    // ---- exclusive multiplicative scan across the wave ----
    const float lp = om0 * om1;
    float inc = lp;
    #pragma unroll
    for (int off = 1; off < 64; off <<= 1) {
        const float q = __shfl_up(inc, off, 64);
        if (lane >= off) inc *= q;
    }
    float Texc = __shfl_up(inc, 1, 64);
    if (lane == 0) Texc = 1.0f;

    const float T0 = Texc;
    const float T1 = Texc * om0;
    const float a0 = (T0 > 1e-4f) ? 1.0f : 0.0f;
    const float a1 = (T1 > 1e-4f) ? 1.0f : 0.0f;
    const float w0 = T0 * al0 * a0;
    const float w1 = T1 * al1 * a1;

    float cr = w0 * rr0 + w1 * rr1;
    float cg = w0 * rg0 + w1 * rg1;
    float cb = w0 * rb0 + w1 * rb1;
    float tp = (a0 > 0.0f ? om0 : 1.0f) * (a1 > 0.0f ? om1 : 1.0f);

    #pragma unroll
    for (int off = 32; off > 0; off >>= 1) {
        cr += __shfl_xor(cr, off, 64);
        cg += __shfl_xor(cg, off, 64);
        cb += __shfl_xor(cb, off, 64);
        tp *= __shfl_xor(tp, off, 64);
    }

    if (lane == 0) {
        out[ray * 3 + 0] = cr;
        out[ray * 3 + 1] = cg;
        out[ray * 3 + 2] = cb;
        out[NRAYS * 3 + ray] = tp;
    }
}

extern "C" void kernel_launch(void* const* d_in, const int* in_sizes, int n_in,
                              void* d_out, int out_size, void* d_ws, size_t ws_size,
                              hipStream_t stream) {
    const float* orig = (const float*)d_in[0];
    const float* dirs = (const float*)d_in[1];
    const float* tmin = (const float*)d_in[2];
    const float* tmax = (const float*)d_in[3];
    const float* W1   = (const float*)d_in[4];
    const float* b1   = (const float*)d_in[5];
    const float* W2   = (const float*)d_in[6];
    const float* b2   = (const float*)d_in[7];
    const float* V1   = (const float*)d_in[8];
    const float* c1   = (const float*)d_in[9];
    const float* V2   = (const float*)d_in[10];
    const float* c2   = (const float*)d_in[11];
    float* dtp = (float*)d_ws;

    dt_kernel<<<1, 256, 0, stream>>>(tmin, tmax, dtp);
    march_kernel<<<NRAYS / 4, 256, 0, stream>>>(orig, dirs, tmin, tmax,
                                                W1, b1, W2, b2, V1, c1, V2, c2,
                                                dtp, (float*)d_out);
}

// Round 5
// 414.732 us; speedup vs baseline: 14.0037x; 12.7561x over previous
//
#include <hip/hip_runtime.h>
#include <hip/hip_bf16.h>

#define NRAYS 8192
#define SAMP  128
#define HID   64
#define DVD   27
#define NFEAT 15

// sin(x), cos(x) via hardware v_sin/v_cos (take REVOLUTIONS; explicit fract
// reduction keeps inside the valid HW domain).
static __device__ __forceinline__ float sin_fast(float x) {
    float r = x * 0.15915494309189535f;   // x / (2*pi)
    r = r - floorf(r);
    return __builtin_amdgcn_sinf(r);
}
static __device__ __forceinline__ float cos_fast(float x) {
    float r = x * 0.15915494309189535f;
    r = r - floorf(r);
    return __builtin_amdgcn_cosf(r);
}

// ---------------------------------------------------------------------------
// Kernel 1: dt = mean(tmax - tmin) / S   (global scalar -> d_ws[0])
// ---------------------------------------------------------------------------
__global__ void dt_kernel(const float* __restrict__ tmin,
                          const float* __restrict__ tmax,
                          float* __restrict__ dt_out) {
    __shared__ float red[256];
    float s = 0.0f;
    for (int i = threadIdx.x; i < NRAYS; i += 256)
        s += tmax[i] - tmin[i];
    red[threadIdx.x] = s;
    __syncthreads();
    for (int off = 128; off > 0; off >>= 1) {
        if (threadIdx.x < off) red[threadIdx.x] += red[threadIdx.x + off];
        __syncthreads();
    }
    if (threadIdx.x == 0)
        dt_out[0] = red[0] / (float)NRAYS / (float)SAMP;
}

// ---------------------------------------------------------------------------
// Kernel 2: one wave per ray; each lane handles samples 2*lane, 2*lane+1,
// strictly sequentially. Hidden layers computed in chunks of 16 neurons with
// JIT-recomputed encodings -> max live array = 16 regs -> no scratch spill.
// Weights staged fp32 in LDS, all reads wave-uniform broadcasts.
// ---------------------------------------------------------------------------
__global__ void __launch_bounds__(256)
march_kernel(const float* __restrict__ orig,
             const float* __restrict__ dirs,
             const float* __restrict__ tmin,
             const float* __restrict__ tmax,
             const float* __restrict__ W1,
             const float* __restrict__ b1,
             const float* __restrict__ W2,
             const float* __restrict__ b2,
             const float* __restrict__ V1,
             const float* __restrict__ c1,
             const float* __restrict__ V2,
             const float* __restrict__ c2,
             const float* __restrict__ dtp,
             float* __restrict__ out) {
    __shared__ float sW1[63 * HID];   // 4032 floats, row-major [k][j]
    __shared__ float sb1[HID];
    __shared__ float sW2[HID * 16];   // [k][j]
    __shared__ float sb2[16];
    __shared__ float sV1[42 * HID];   // [k][j]
    __shared__ float sc1[HID];
    __shared__ float sV2t[3 * HID];   // TRANSPOSED: [o][k]
    __shared__ float sc2[3];
    __shared__ float sVde[4 * DVD];   // per-wave view-dir encoding

    const int tid = threadIdx.x;
    for (int i = tid; i < 63 * HID; i += 256) sW1[i] = W1[i];
    for (int i = tid; i < HID;      i += 256) sb1[i] = b1[i];
    for (int i = tid; i < HID * 16; i += 256) sW2[i] = W2[i];
    for (int i = tid; i < 16;       i += 256) sb2[i] = b2[i];
    for (int i = tid; i < 42 * HID; i += 256) sV1[i] = V1[i];
    for (int i = tid; i < HID;      i += 256) sc1[i] = c1[i];
    for (int i = tid; i < HID * 3;  i += 256) {
        const int k = i / 3, o = i - 3 * k;       // V2 is [k][o]
        sV2t[o * HID + k] = V2[i];
    }
    for (int i = tid; i < 3;        i += 256) sc2[i] = c2[i];

    const int lane = tid & 63;
    const int wave = tid >> 6;
    const int ray  = blockIdx.x * 4 + wave;

    const float ox = orig[ray * 3 + 0];
    const float oy = orig[ray * 3 + 1];
    const float oz = orig[ray * 3 + 2];
    const float dx = dirs[ray * 3 + 0];
    const float dy = dirs[ray * 3 + 1];
    const float dz = dirs[ray * 3 + 2];
    const float t0 = tmin[ray];
    const float trange = tmax[ray] - t0;
    const float dt = dtp[0];

    // view-dir encoding -> per-wave LDS (element `lane` computed by lanes 0..26)
    {
        const float nrm = sqrtf(dx * dx + dy * dy + dz * dz);
        const float inv = 1.0f / (nrm + 1e-8f);
        const float vx = dx * inv, vy = dy * inv, vz = dz * inv;
        if (lane < DVD) {
            float val;
            if (lane < 3) {
                val = (lane == 0) ? vx : ((lane == 1) ? vy : vz);
            } else {
                const int q = lane - 3;
                const int b = q / 6;
                const int r = q - 6 * b;
                const bool isSin = (r < 3);
                const int d = isSin ? r : (r - 3);
                const float comp = (d == 0) ? vx : ((d == 1) ? vy : vz);
                const float a = (float)(1 << b) * comp;
                val = isSin ? sin_fast(a) : cos_fast(a);
            }
            sVde[wave * DVD + lane] = val;
        }
    }
    __syncthreads();

    // per-sample results, named scalars
    float om0 = 1.0f, om1 = 1.0f, al0 = 0.0f, al1 = 0.0f;
    float rr0 = 0.0f, rg0 = 0.0f, rb0 = 0.0f;
    float rr1 = 0.0f, rg1 = 0.0f, rb1 = 0.0f;

    #pragma unroll 1
    for (int ss = 0; ss < 2; ss++) {
        const int s = lane * 2 + ss;
        const float u = (float)s * (1.0f / (float)(SAMP - 1));
        const float t = t0 + u * trange;
        const float px = ox + dx * t;
        const float py = oy + dy * t;
        const float pz = oz + dz * t;

        // ---- layer 1 + fold into o[16] via W2, chunked 16 neurons ----
        float o[16];
        #pragma unroll
        for (int j = 0; j < 16; j++) o[j] = sb2[j];

        #pragma unroll 1
        for (int c = 0; c < 4; c++) {
            const int cj = c * 16;
            float hc[16];
            #pragma unroll
            for (int j = 0; j < 16; j++) hc[j] = sb1[cj + j];
            // identity rows 0..2
            #pragma unroll
            for (int j = 0; j < 16; j++) hc[j] += px * sW1[0 * HID + cj + j];
            #pragma unroll
            for (int j = 0; j < 16; j++) hc[j] += py * sW1[1 * HID + cj + j];
            #pragma unroll
            for (int j = 0; j < 16; j++) hc[j] += pz * sW1[2 * HID + cj + j];
            // band rows, sin/cos recomputed just-in-time (dies immediately)
            #pragma unroll 1
            for (int b = 0; b < 10; b++) {
                const float f = (float)(1 << b);
                {
                    const float sv = sin_fast(f * px), cv = cos_fast(f * px);
                    const int rs = (3 + 6 * b + 0) * HID + cj;
                    const int rc = rs + 3 * HID;
                    #pragma unroll
                    for (int j = 0; j < 16; j++)
                        hc[j] += sv * sW1[rs + j] + cv * sW1[rc + j];
                }
                {
                    const float sv = sin_fast(f * py), cv = cos_fast(f * py);
                    const int rs = (3 + 6 * b + 1) * HID + cj;
                    const int rc = rs + 3 * HID;
                    #pragma unroll
                    for (int j = 0; j < 16; j++)
                        hc[j] += sv * sW1[rs + j] + cv * sW1[rc + j];
                }
                {
                    const float sv = sin_fast(f * pz), cv = cos_fast(f * pz);
                    const int rs = (3 + 6 * b + 2) * HID + cj;
                    const int rc = rs + 3 * HID;
                    #pragma unroll
                    for (int j = 0; j < 16; j++)
                        hc[j] += sv * sW1[rs + j] + cv * sW1[rc + j];
                }
            }
            // fold relu(hc) into o via W2 rows cj..cj+15
            #pragma unroll
            for (int j = 0; j < 16; j++) {
                const float hv = fmaxf(hc[j], 0.0f);
                const int wr = (cj + j) * 16;
                #pragma unroll
                for (int jj = 0; jj < 16; jj++) o[jj] += hv * sW2[wr + jj];
            }
        }
        const float sigma = fmaxf(o[0], 0.0f);

        // ---- layer g + fold into rgb via V2t, chunked 16 neurons ----
        float r0 = sc2[0], r1 = sc2[1], r2 = sc2[2];
        #pragma unroll 1
        for (int c = 0; c < 4; c++) {
            const int cj = c * 16;
            float gc[16];
            #pragma unroll
            for (int j = 0; j < 16; j++) gc[j] = sc1[cj + j];
            // feature rows (o[1..15], static indices)
            #pragma unroll
            for (int k = 0; k < NFEAT; k++) {
                const float e = o[1 + k];
                #pragma unroll
                for (int j = 0; j < 16; j++) gc[j] += e * sV1[k * HID + cj + j];
            }
            // view-dir rows (broadcast from LDS, rolled)
            #pragma unroll 1
            for (int k = 0; k < DVD; k++) {
                const float e = sVde[wave * DVD + k];
                #pragma unroll
                for (int j = 0; j < 16; j++)
                    gc[j] += e * sV1[(NFEAT + k) * HID + cj + j];
            }
            // fold relu(gc) into rgb accumulators via transposed V2
            #pragma unroll
            for (int j = 0; j < 16; j++) {
                const float gv = fmaxf(gc[j], 0.0f);
                r0 += gv * sV2t[0 * HID + cj + j];
                r1 += gv * sV2t[1 * HID + cj + j];
                r2 += gv * sV2t[2 * HID + cj + j];
            }
        }

        const float sr = 1.0f / (1.0f + __expf(-r0));
        const float sg = 1.0f / (1.0f + __expf(-r1));
        const float sb = 1.0f / (1.0f + __expf(-r2));
        const float alpha = 1.0f - __expf(-sigma * dt);
        const float omv = 1.0f - alpha;

        if (ss == 0) { om0 = omv; al0 = alpha; rr0 = sr; rg0 = sg; rb0 = sb; }
        else         { om1 = omv; al1 = alpha; rr1 = sr; rg1 = sg; rb1 = sb; }
    }

    // ---- exclusive multiplicative scan across the wave ----
    const float lp = om0 * om1;
    float inc = lp;
    #pragma unroll
    for (int off = 1; off < 64; off <<= 1) {
        const float q = __shfl_up(inc, off, 64);
        if (lane >= off) inc *= q;
    }
    float Texc = __shfl_up(inc, 1, 64);
    if (lane == 0) Texc = 1.0f;

    const float T0 = Texc;
    const float T1 = Texc * om0;
    const float a0 = (T0 > 1e-4f) ? 1.0f : 0.0f;
    const float a1 = (T1 > 1e-4f) ? 1.0f : 0.0f;
    const float w0 = T0 * al0 * a0;
    const float w1 = T1 * al1 * a1;

    float cr = w0 * rr0 + w1 * rr1;
    float cg = w0 * rg0 + w1 * rg1;
    float cb = w0 * rb0 + w1 * rb1;
    float tp = (a0 > 0.0f ? om0 : 1.0f) * (a1 > 0.0f ? om1 : 1.0f);

    #pragma unroll
    for (int off = 32; off > 0; off >>= 1) {
        cr += __shfl_xor(cr, off, 64);
        cg += __shfl_xor(cg, off, 64);
        cb += __shfl_xor(cb, off, 64);
        tp *= __shfl_xor(tp, off, 64);
    }

    if (lane == 0) {
        out[ray * 3 + 0] = cr;
        out[ray * 3 + 1] = cg;
        out[ray * 3 + 2] = cb;
        out[NRAYS * 3 + ray] = tp;
    }
}

extern "C" void kernel_launch(void* const* d_in, const int* in_sizes, int n_in,
                              void* d_out, int out_size, void* d_ws, size_t ws_size,
                              hipStream_t stream) {
    const float* orig = (const float*)d_in[0];
    const float* dirs = (const float*)d_in[1];
    const float* tmin = (const float*)d_in[2];
    const float* tmax = (const float*)d_in[3];
    const float* W1   = (const float*)d_in[4];
    const float* b1   = (const float*)d_in[5];
    const float* W2   = (const float*)d_in[6];
    const float* b2   = (const float*)d_in[7];
    const float* V1   = (const float*)d_in[8];
    const float* c1   = (const float*)d_in[9];
    const float* V2   = (const float*)d_in[10];
    const float* c2   = (const float*)d_in[11];
    float* dtp = (float*)d_ws;

    dt_kernel<<<1, 256, 0, stream>>>(tmin, tmax, dtp);
    march_kernel<<<NRAYS / 4, 256, 0, stream>>>(orig, dirs, tmin, tmax,
                                                W1, b1, W2, b2, V1, c1, V2, c2,
                                                dtp, (float*)d_out);
}

// Round 6
// 347.139 us; speedup vs baseline: 16.7305x; 1.1947x over previous
//
#include <hip/hip_runtime.h>
#include <hip/hip_bf16.h>

#define NRAYS 8192
#define SAMP  128
#define HID   64
#define DVD   27
#define NFEAT 15

typedef float f2 __attribute__((ext_vector_type(2)));

// sin/cos via hardware v_sin/v_cos (take REVOLUTIONS; fract reduction keeps
// inside the valid HW domain).
static __device__ __forceinline__ float sin_fast(float x) {
    float r = x * 0.15915494309189535f;
    r = r - floorf(r);
    return __builtin_amdgcn_sinf(r);
}
static __device__ __forceinline__ float cos_fast(float x) {
    float r = x * 0.15915494309189535f;
    r = r - floorf(r);
    return __builtin_amdgcn_cosf(r);
}

// ---------------------------------------------------------------------------
// Kernel 1: dt = mean(tmax - tmin) / S   (global scalar -> d_ws[0])
// ---------------------------------------------------------------------------
__global__ void dt_kernel(const float* __restrict__ tmin,
                          const float* __restrict__ tmax,
                          float* __restrict__ dt_out) {
    __shared__ float red[256];
    float s = 0.0f;
    for (int i = threadIdx.x; i < NRAYS; i += 256)
        s += tmax[i] - tmin[i];
    red[threadIdx.x] = s;
    __syncthreads();
    for (int off = 128; off > 0; off >>= 1) {
        if (threadIdx.x < off) red[threadIdx.x] += red[threadIdx.x + off];
        __syncthreads();
    }
    if (threadIdx.x == 0)
        dt_out[0] = red[0] / (float)NRAYS / (float)SAMP;
}

// ---------------------------------------------------------------------------
// Kernel 2: one wave per ray; each lane handles samples 2*lane, 2*lane+1
// TOGETHER with packed float2 accumulators -> each LDS weight read feeds 2
// samples (v_pk_fma_f32). Chunks of 16 neurons, JIT-recomputed encodings.
// ---------------------------------------------------------------------------
__global__ void __launch_bounds__(256)
march_kernel(const float* __restrict__ orig,
             const float* __restrict__ dirs,
             const float* __restrict__ tmin,
             const float* __restrict__ tmax,
             const float* __restrict__ W1,
             const float* __restrict__ b1,
             const float* __restrict__ W2,
             const float* __restrict__ b2,
             const float* __restrict__ V1,
             const float* __restrict__ c1,
             const float* __restrict__ V2,
             const float* __restrict__ c2,
             const float* __restrict__ dtp,
             float* __restrict__ out) {
    __shared__ float sW1[63 * HID];   // [k][j]
    __shared__ float sb1[HID];
    __shared__ float sW2[HID * 16];   // [k][j]
    __shared__ float sb2[16];
    __shared__ float sV1[42 * HID];   // [k][j]
    __shared__ float sc1[HID];
    __shared__ float sV2t[3 * HID];   // TRANSPOSED: [o][k]
    __shared__ float sc2[3];
    __shared__ float sVde[4 * DVD];   // per-wave view-dir encoding

    const int tid = threadIdx.x;
    for (int i = tid; i < 63 * HID; i += 256) sW1[i] = W1[i];
    for (int i = tid; i < HID;      i += 256) sb1[i] = b1[i];
    for (int i = tid; i < HID * 16; i += 256) sW2[i] = W2[i];
    for (int i = tid; i < 16;       i += 256) sb2[i] = b2[i];
    for (int i = tid; i < 42 * HID; i += 256) sV1[i] = V1[i];
    for (int i = tid; i < HID;      i += 256) sc1[i] = c1[i];
    for (int i = tid; i < HID * 3;  i += 256) {
        const int k = i / 3, o = i - 3 * k;       // V2 is [k][o]
        sV2t[o * HID + k] = V2[i];
    }
    for (int i = tid; i < 3;        i += 256) sc2[i] = c2[i];

    const int lane = tid & 63;
    const int wave = tid >> 6;
    const int ray  = blockIdx.x * 4 + wave;

    const float ox = orig[ray * 3 + 0];
    const float oy = orig[ray * 3 + 1];
    const float oz = orig[ray * 3 + 2];
    const float dx = dirs[ray * 3 + 0];
    const float dy = dirs[ray * 3 + 1];
    const float dz = dirs[ray * 3 + 2];
    const float t0 = tmin[ray];
    const float trange = tmax[ray] - t0;
    const float dt = dtp[0];

    // view-dir encoding -> per-wave LDS
    {
        const float nrm = sqrtf(dx * dx + dy * dy + dz * dz);
        const float inv = 1.0f / (nrm + 1e-8f);
        const float vx = dx * inv, vy = dy * inv, vz = dz * inv;
        if (lane < DVD) {
            float val;
            if (lane < 3) {
                val = (lane == 0) ? vx : ((lane == 1) ? vy : vz);
            } else {
                const int q = lane - 3;
                const int b = q / 6;
                const int r = q - 6 * b;
                const bool isSin = (r < 3);
                const int d = isSin ? r : (r - 3);
                const float comp = (d == 0) ? vx : ((d == 1) ? vy : vz);
                const float a = (float)(1 << b) * comp;
                val = isSin ? sin_fast(a) : cos_fast(a);
            }
            sVde[wave * DVD + lane] = val;
        }
    }
    __syncthreads();

    // two samples per lane, processed together (packed .x = s0, .y = s1)
    const int s0 = lane * 2;
    const float u0 = (float)s0 * (1.0f / (float)(SAMP - 1));
    const float u1 = (float)(s0 + 1) * (1.0f / (float)(SAMP - 1));
    const float ta = t0 + u0 * trange;
    const float tb = t0 + u1 * trange;
    const f2 px = {ox + dx * ta, ox + dx * tb};
    const f2 py = {oy + dy * ta, oy + dy * tb};
    const f2 pz = {oz + dz * ta, oz + dz * tb};

    // ---- layer 1 folded into o2[16] via W2, chunked 16 neurons ----
    f2 o2[16];
    #pragma unroll
    for (int j = 0; j < 16; j++) o2[j] = (f2){sb2[j], sb2[j]};

    #pragma unroll 1
    for (int c = 0; c < 4; c++) {
        const int cj = c * 16;
        f2 hc[16];
        #pragma unroll
        for (int j = 0; j < 16; j++) hc[j] = (f2){sb1[cj + j], sb1[cj + j]};
        #pragma unroll
        for (int j = 0; j < 16; j++) {
            const float w = sW1[0 * HID + cj + j];
            hc[j] += px * (f2){w, w};
        }
        #pragma unroll
        for (int j = 0; j < 16; j++) {
            const float w = sW1[1 * HID + cj + j];
            hc[j] += py * (f2){w, w};
        }
        #pragma unroll
        for (int j = 0; j < 16; j++) {
            const float w = sW1[2 * HID + cj + j];
            hc[j] += pz * (f2){w, w};
        }
        // band rows; sin/cos recomputed just-in-time for both samples
        #pragma unroll 1
        for (int b = 0; b < 10; b++) {
            const float f = (float)(1 << b);
            {
                const f2 sv = {sin_fast(f * px.x), sin_fast(f * px.y)};
                const f2 cv = {cos_fast(f * px.x), cos_fast(f * px.y)};
                const int rs = (3 + 6 * b + 0) * HID + cj;
                const int rc = rs + 3 * HID;
                #pragma unroll
                for (int j = 0; j < 16; j++) {
                    const float ws = sW1[rs + j], wc = sW1[rc + j];
                    hc[j] += sv * (f2){ws, ws} + cv * (f2){wc, wc};
                }
            }
            {
                const f2 sv = {sin_fast(f * py.x), sin_fast(f * py.y)};
                const f2 cv = {cos_fast(f * py.x), cos_fast(f * py.y)};
                const int rs = (3 + 6 * b + 1) * HID + cj;
                const int rc = rs + 3 * HID;
                #pragma unroll
                for (int j = 0; j < 16; j++) {
                    const float ws = sW1[rs + j], wc = sW1[rc + j];
                    hc[j] += sv * (f2){ws, ws} + cv * (f2){wc, wc};
                }
            }
            {
                const f2 sv = {sin_fast(f * pz.x), sin_fast(f * pz.y)};
                const f2 cv = {cos_fast(f * pz.x), cos_fast(f * pz.y)};
                const int rs = (3 + 6 * b + 2) * HID + cj;
                const int rc = rs + 3 * HID;
                #pragma unroll
                for (int j = 0; j < 16; j++) {
                    const float ws = sW1[rs + j], wc = sW1[rc + j];
                    hc[j] += sv * (f2){ws, ws} + cv * (f2){wc, wc};
                }
            }
        }
        // fold relu(hc) into o2 via W2 rows cj..cj+15
        #pragma unroll
        for (int j = 0; j < 16; j++) {
            const f2 hv = {fmaxf(hc[j].x, 0.0f), fmaxf(hc[j].y, 0.0f)};
            const int wr = (cj + j) * 16;
            #pragma unroll
            for (int jj = 0; jj < 16; jj++) {
                const float w = sW2[wr + jj];
                o2[jj] += hv * (f2){w, w};
            }
        }
    }
    const f2 sigma = {fmaxf(o2[0].x, 0.0f), fmaxf(o2[0].y, 0.0f)};

    // ---- layer g folded into rgb via V2t, chunked 16 neurons ----
    f2 r0 = {sc2[0], sc2[0]}, r1 = {sc2[1], sc2[1]}, r2 = {sc2[2], sc2[2]};
    #pragma unroll 1
    for (int c = 0; c < 4; c++) {
        const int cj = c * 16;
        f2 gc[16];
        #pragma unroll
        for (int j = 0; j < 16; j++) gc[j] = (f2){sc1[cj + j], sc1[cj + j]};
        #pragma unroll
        for (int k = 0; k < NFEAT; k++) {
            const f2 e = o2[1 + k];
            #pragma unroll
            for (int j = 0; j < 16; j++) {
                const float w = sV1[k * HID + cj + j];
                gc[j] += e * (f2){w, w};
            }
        }
        #pragma unroll 1
        for (int k = 0; k < DVD; k++) {   // e uniform per ray (LDS broadcast)
            const float e = sVde[wave * DVD + k];
            #pragma unroll
            for (int j = 0; j < 16; j++) {
                const float w = sV1[(NFEAT + k) * HID + cj + j];
                gc[j] += (f2){e * w, e * w};
            }
        }
        #pragma unroll
        for (int j = 0; j < 16; j++) {
            const f2 gv = {fmaxf(gc[j].x, 0.0f), fmaxf(gc[j].y, 0.0f)};
            const float w0v = sV2t[0 * HID + cj + j];
            const float w1v = sV2t[1 * HID + cj + j];
            const float w2v = sV2t[2 * HID + cj + j];
            r0 += gv * (f2){w0v, w0v};
            r1 += gv * (f2){w1v, w1v};
            r2 += gv * (f2){w2v, w2v};
        }
    }

    const float rr0 = 1.0f / (1.0f + __expf(-r0.x));
    const float rr1 = 1.0f / (1.0f + __expf(-r0.y));
    const float rg0 = 1.0f / (1.0f + __expf(-r1.x));
    const float rg1 = 1.0f / (1.0f + __expf(-r1.y));
    const float rb0 = 1.0f / (1.0f + __expf(-r2.x));
    const float rb1 = 1.0f / (1.0f + __expf(-r2.y));
    const float al0 = 1.0f - __expf(-sigma.x * dt);
    const float al1 = 1.0f - __expf(-sigma.y * dt);
    const float om0 = 1.0f - al0;
    const float om1 = 1.0f - al1;

    // ---- exclusive multiplicative scan across the wave ----
    float inc = om0 * om1;
    #pragma unroll
    for (int off = 1; off < 64; off <<= 1) {
        const float q = __shfl_up(inc, off, 64);
        if (lane >= off) inc *= q;
    }
    float Texc = __shfl_up(inc, 1, 64);
    if (lane == 0) Texc = 1.0f;

    const float T0 = Texc;
    const float T1 = Texc * om0;
    const float a0 = (T0 > 1e-4f) ? 1.0f : 0.0f;
    const float a1 = (T1 > 1e-4f) ? 1.0f : 0.0f;
    const float w0 = T0 * al0 * a0;
    const float w1 = T1 * al1 * a1;

    float cr = w0 * rr0 + w1 * rr1;
    float cg = w0 * rg0 + w1 * rg1;
    float cb = w0 * rb0 + w1 * rb1;
    float tp = (a0 > 0.0f ? om0 : 1.0f) * (a1 > 0.0f ? om1 : 1.0f);

    #pragma unroll
    for (int off = 32; off > 0; off >>= 1) {
        cr += __shfl_xor(cr, off, 64);
        cg += __shfl_xor(cg, off, 64);
        cb += __shfl_xor(cb, off, 64);
        tp *= __shfl_xor(tp, off, 64);
    }

    if (lane == 0) {
        out[ray * 3 + 0] = cr;
        out[ray * 3 + 1] = cg;
        out[ray * 3 + 2] = cb;
        out[NRAYS * 3 + ray] = tp;
    }
}

extern "C" void kernel_launch(void* const* d_in, const int* in_sizes, int n_in,
                              void* d_out, int out_size, void* d_ws, size_t ws_size,
                              hipStream_t stream) {
    const float* orig = (const float*)d_in[0];
    const float* dirs = (const float*)d_in[1];
    const float* tmin = (const float*)d_in[2];
    const float* tmax = (const float*)d_in[3];
    const float* W1   = (const float*)d_in[4];
    const float* b1   = (const float*)d_in[5];
    const float* W2   = (const float*)d_in[6];
    const float* b2   = (const float*)d_in[7];
    const float* V1   = (const float*)d_in[8];
    const float* c1   = (const float*)d_in[9];
    const float* V2   = (const float*)d_in[10];
    const float* c2   = (const float*)d_in[11];
    float* dtp = (float*)d_ws;

    dt_kernel<<<1, 256, 0, stream>>>(tmin, tmax, dtp);
    march_kernel<<<NRAYS / 4, 256, 0, stream>>>(orig, dirs, tmin, tmax,
                                                W1, b1, W2, b2, V1, c1, V2, c2,
                                                dtp, (float*)d_out);
}

// Round 7
// 207.492 us; speedup vs baseline: 27.9904x; 1.6730x over previous
//
#include <hip/hip_runtime.h>
#include <hip/hip_bf16.h>

#define NRAYS 8192
#define SAMP  128
#define HID   64
#define DVD   27
#define NFEAT 15

typedef float  f32x4  __attribute__((ext_vector_type(4)));
typedef short  short8 __attribute__((ext_vector_type(8)));

// sin/cos via hardware v_sin/v_cos (REVOLUTIONS; fract reduction for domain).
static __device__ __forceinline__ float sin_fast(float x) {
    float r = x * 0.15915494309189535f;
    r = r - floorf(r);
    return __builtin_amdgcn_sinf(r);
}
static __device__ __forceinline__ float cos_fast(float x) {
    float r = x * 0.15915494309189535f;
    r = r - floorf(r);
    return __builtin_amdgcn_cosf(r);
}
// fp32 -> bf16 (RNE), as raw short
static __device__ __forceinline__ short f2bf(float x) {
    unsigned u = __float_as_uint(x);
    u += 0x7FFF + ((u >> 16) & 1);
    return (short)(u >> 16);
}

// ---------------------------------------------------------------------------
// Kernel 1: dt = mean(tmax - tmin) / S   (global scalar -> d_ws[0])
// ---------------------------------------------------------------------------
__global__ void dt_kernel(const float* __restrict__ tmin,
                          const float* __restrict__ tmax,
                          float* __restrict__ dt_out) {
    __shared__ float red[256];
    float s = 0.0f;
    for (int i = threadIdx.x; i < NRAYS; i += 256)
        s += tmax[i] - tmin[i];
    red[threadIdx.x] = s;
    __syncthreads();
    for (int off = 128; off > 0; off >>= 1) {
        if (threadIdx.x < off) red[threadIdx.x] += red[threadIdx.x + off];
        __syncthreads();
    }
    if (threadIdx.x == 0)
        dt_out[0] = red[0] / (float)NRAYS / (float)SAMP;
}

// ---------------------------------------------------------------------------
// Kernel 2: MFMA formulation. 1 block = 4 waves = 4 rays. Each wave runs its
// ray in 4 quarters of 32 samples (M=32). bf16 operands in LDS; weights
// transposed [n][k] and hoisted into register B-fragments once. C->A layout
// change via LDS roundtrip. vde@V1 precomputed per ray in fp32 (gvde).
// ---------------------------------------------------------------------------
__global__ void __launch_bounds__(256)
march_kernel(const float* __restrict__ orig,
             const float* __restrict__ dirs,
             const float* __restrict__ tmin,
             const float* __restrict__ tmax,
             const float* __restrict__ W1,
             const float* __restrict__ b1,
             const float* __restrict__ W2,
             const float* __restrict__ b2,
             const float* __restrict__ V1,
             const float* __restrict__ c1,
             const float* __restrict__ V2,
             const float* __restrict__ c2,
             const float* __restrict__ dtp,
             float* __restrict__ out) {
    __shared__ __align__(16) short sW1t[64 * 72];   // W1^T [n][k], k<63 real
    __shared__ __align__(16) short sW2t[16 * 72];   // W2^T [n][k]
    __shared__ __align__(16) short sV1t[64 * 40];   // V1^T [n][k], k<15 real
    __shared__ __align__(16) short sV2t[16 * 72];   // V2^T [n][k], n<3 real
    __shared__ float sb1v[64], sb2v[16], sc1v[64], sc2v[4];
    __shared__ float sVde[4][DVD];
    __shared__ __align__(16) short sE[4][32 * 72];  // per-wave E/h/g buffer
    __shared__ __align__(16) short sG[4][32 * 40];  // per-wave G_in buffer
    __shared__ float sOm[4][128], sAl[4][128];
    __shared__ float sRgb[4][128 * 4];

    const int tid  = threadIdx.x;
    const int lane = tid & 63;
    const int wave = tid >> 6;
    const int ray  = blockIdx.x * 4 + wave;

    // ---- stage weights (transposed, bf16, zero-padded) ----
    for (int i = tid; i < 64 * 72; i += 256) {
        const int n = i / 72, k = i - 72 * n;
        sW1t[i] = (k < 63) ? f2bf(W1[k * 64 + n]) : (short)0;
    }
    for (int i = tid; i < 16 * 72; i += 256) {
        const int n = i / 72, k = i - 72 * n;
        sW2t[i] = (k < 64) ? f2bf(W2[k * 16 + n]) : (short)0;
    }
    for (int i = tid; i < 64 * 40; i += 256) {
        const int n = i / 40, k = i - 40 * n;
        sV1t[i] = (k < NFEAT) ? f2bf(V1[k * 64 + n]) : (short)0;
    }
    for (int i = tid; i < 16 * 72; i += 256) {
        const int n = i / 72, k = i - 72 * n;
        sV2t[i] = (k < 64 && n < 3) ? f2bf(V2[k * 3 + n]) : (short)0;
    }
    for (int i = tid; i < 64; i += 256) sb1v[i] = b1[i];
    for (int i = tid; i < 16; i += 256) sb2v[i] = b2[i];
    for (int i = tid; i < 64; i += 256) sc1v[i] = c1[i];
    if (tid < 4) sc2v[tid] = (tid < 3) ? c2[tid] : 0.0f;
    for (int i = tid; i < 4 * 32 * 40; i += 256) (&sG[0][0])[i] = 0;

    // ---- per-ray scalars ----
    const float ox = orig[ray * 3 + 0];
    const float oy = orig[ray * 3 + 1];
    const float oz = orig[ray * 3 + 2];
    const float dx = dirs[ray * 3 + 0];
    const float dy = dirs[ray * 3 + 1];
    const float dz = dirs[ray * 3 + 2];
    const float t0v = tmin[ray];
    const float trange = tmax[ray] - t0v;
    const float dtv = dtp[0];

    // ---- view-dir encoding (fp32) -> sVde ----
    {
        const float nrm = sqrtf(dx * dx + dy * dy + dz * dz);
        const float inv = 1.0f / (nrm + 1e-8f);
        const float vx = dx * inv, vy = dy * inv, vz = dz * inv;
        if (lane < DVD) {
            float val;
            if (lane < 3) {
                val = (lane == 0) ? vx : ((lane == 1) ? vy : vz);
            } else {
                const int q = lane - 3;
                const int b = q / 6;
                const int r = q - 6 * b;
                const bool isSin = (r < 3);
                const int d = isSin ? r : (r - 3);
                const float comp = (d == 0) ? vx : ((d == 1) ? vy : vz);
                const float a = (float)(1 << b) * comp;
                val = isSin ? sin_fast(a) : cos_fast(a);
            }
            sVde[wave][lane] = val;
        }
    }
    __syncthreads();

    const int nfr  = lane & 15;   // n (or m) within a 16-tile
    const int quad = lane >> 4;

    // ---- hoist B-fragments into registers (once) ----
    short8 w1f[4][2], w2f[2], v1f[4], v2f[2];
    #pragma unroll
    for (int nt = 0; nt < 4; nt++)
        #pragma unroll
        for (int kt = 0; kt < 2; kt++)
            w1f[nt][kt] = *(const short8*)&sW1t[(nfr + 16 * nt) * 72 + quad * 8 + kt * 32];
    #pragma unroll
    for (int kt = 0; kt < 2; kt++)
        w2f[kt] = *(const short8*)&sW2t[nfr * 72 + quad * 8 + kt * 32];
    #pragma unroll
    for (int nt = 0; nt < 4; nt++)
        v1f[nt] = *(const short8*)&sV1t[(nfr + 16 * nt) * 40 + quad * 8];
    #pragma unroll
    for (int kt = 0; kt < 2; kt++)
        v2f[kt] = *(const short8*)&sV2t[nfr * 72 + quad * 8 + kt * 32];

    // ---- gvde[n] = sum_q vde[q] * V1[15+q][n] (fp32, per ray) ----
    float gv[4] = {0.0f, 0.0f, 0.0f, 0.0f};
    #pragma unroll 1
    for (int q = 0; q < DVD; q++) {
        const float e = sVde[wave][q];
        const float* vrow = V1 + (NFEAT + q) * 64;
        #pragma unroll
        for (int nt = 0; nt < 4; nt++) gv[nt] += e * vrow[nfr + 16 * nt];
    }

    const int sl   = lane >> 1;   // local sample 0..31 (enc phase)
    const int half = lane & 1;
    short* const myE = sE[wave];
    short* const myG = sG[wave];

    #pragma unroll 1
    for (int qq = 0; qq < 4; qq++) {
        __syncthreads();   // protect myE WAR vs previous quarter's V2 reads
        // --- positional encodings for 32 samples (2 lanes/sample) ---
        {
            const int s = qq * 32 + sl;
            const float t = t0v + (float)s * (1.0f / 127.0f) * trange;
            const float px = ox + dx * t, py = oy + dy * t, pz = oz + dz * t;
            short* Erow = &myE[sl * 72];
            if (half == 0) {
                Erow[0] = f2bf(px); Erow[1] = f2bf(py); Erow[2] = f2bf(pz);
                #pragma unroll 1
                for (int b = 0; b < 5; b++) {
                    const float f = (float)(1 << b);
                    Erow[3 + 6 * b + 0] = f2bf(sin_fast(f * px));
                    Erow[3 + 6 * b + 1] = f2bf(sin_fast(f * py));
                    Erow[3 + 6 * b + 2] = f2bf(sin_fast(f * pz));
                    Erow[3 + 6 * b + 3] = f2bf(cos_fast(f * px));
                    Erow[3 + 6 * b + 4] = f2bf(cos_fast(f * py));
                    Erow[3 + 6 * b + 5] = f2bf(cos_fast(f * pz));
                }
            } else {
                #pragma unroll 1
                for (int b = 5; b < 10; b++) {
                    const float f = (float)(1 << b);
                    Erow[3 + 6 * b + 0] = f2bf(sin_fast(f * px));
                    Erow[3 + 6 * b + 1] = f2bf(sin_fast(f * py));
                    Erow[3 + 6 * b + 2] = f2bf(sin_fast(f * pz));
                    Erow[3 + 6 * b + 3] = f2bf(cos_fast(f * px));
                    Erow[3 + 6 * b + 4] = f2bf(cos_fast(f * py));
                    Erow[3 + 6 * b + 5] = f2bf(cos_fast(f * pz));
                }
                Erow[63] = 0;
            }
        }
        __syncthreads();
        // --- layer 1: h = relu(E @ W1 + b1) ---
        f32x4 acc1[2][4];
        #pragma unroll
        for (int mt = 0; mt < 2; mt++)
            #pragma unroll
            for (int nt = 0; nt < 4; nt++)
                acc1[mt][nt] = (f32x4){0.0f, 0.0f, 0.0f, 0.0f};
        {
            short8 af[2][2];
            #pragma unroll
            for (int mt = 0; mt < 2; mt++)
                #pragma unroll
                for (int kt = 0; kt < 2; kt++)
                    af[mt][kt] = *(const short8*)&myE[(nfr + 16 * mt) * 72 + quad * 8 + kt * 32];
            #pragma unroll
            for (int mt = 0; mt < 2; mt++)
                #pragma unroll
                for (int nt = 0; nt < 4; nt++)
                    #pragma unroll
                    for (int kt = 0; kt < 2; kt++)
                        acc1[mt][nt] = __builtin_amdgcn_mfma_f32_16x16x32_bf16(
                            af[mt][kt], w1f[nt][kt], acc1[mt][nt], 0, 0, 0);
        }
        __syncthreads();   // E reads done before h overwrites
        #pragma unroll
        for (int mt = 0; mt < 2; mt++)
            #pragma unroll
            for (int nt = 0; nt < 4; nt++)
                #pragma unroll
                for (int r = 0; r < 4; r++) {
                    const int m = 4 * quad + r + 16 * mt;
                    const float hv = fmaxf(acc1[mt][nt][r] + sb1v[nfr + 16 * nt], 0.0f);
                    myE[m * 72 + nfr + 16 * nt] = f2bf(hv);
                }
        __syncthreads();
        // --- W2: O = h @ W2 + b2 ---
        f32x4 acc2[2];
        acc2[0] = (f32x4){0.0f, 0.0f, 0.0f, 0.0f};
        acc2[1] = (f32x4){0.0f, 0.0f, 0.0f, 0.0f};
        {
            short8 ah[2][2];
            #pragma unroll
            for (int mt = 0; mt < 2; mt++)
                #pragma unroll
                for (int kt = 0; kt < 2; kt++)
                    ah[mt][kt] = *(const short8*)&myE[(nfr + 16 * mt) * 72 + quad * 8 + kt * 32];
            #pragma unroll
            for (int mt = 0; mt < 2; mt++)
                #pragma unroll
                for (int kt = 0; kt < 2; kt++)
                    acc2[mt] = __builtin_amdgcn_mfma_f32_16x16x32_bf16(
                        ah[mt][kt], w2f[kt], acc2[mt], 0, 0, 0);
        }
        if (nfr == 0) {
            #pragma unroll
            for (int mt = 0; mt < 2; mt++)
                #pragma unroll
                for (int r = 0; r < 4; r++) {
                    const int m = 4 * quad + r + 16 * mt;
                    const float sg = fmaxf(acc2[mt][r] + sb2v[0], 0.0f);
                    const float al = 1.0f - __expf(-sg * dtv);
                    sAl[wave][qq * 32 + m] = al;
                    sOm[wave][qq * 32 + m] = 1.0f - al;
                }
        } else {
            #pragma unroll
            for (int mt = 0; mt < 2; mt++)
                #pragma unroll
                for (int r = 0; r < 4; r++) {
                    const int m = 4 * quad + r + 16 * mt;
                    myG[m * 40 + (nfr - 1)] = f2bf(acc2[mt][r] + sb2v[nfr]);
                }
        }
        __syncthreads();
        // --- V1: g = relu(G_in @ V1 + c1 + gvde) ---
        f32x4 acc3[2][4];
        #pragma unroll
        for (int mt = 0; mt < 2; mt++)
            #pragma unroll
            for (int nt = 0; nt < 4; nt++)
                acc3[mt][nt] = (f32x4){0.0f, 0.0f, 0.0f, 0.0f};
        {
            short8 ag[2];
            #pragma unroll
            for (int mt = 0; mt < 2; mt++)
                ag[mt] = *(const short8*)&myG[(nfr + 16 * mt) * 40 + quad * 8];
            #pragma unroll
            for (int mt = 0; mt < 2; mt++)
                #pragma unroll
                for (int nt = 0; nt < 4; nt++)
                    acc3[mt][nt] = __builtin_amdgcn_mfma_f32_16x16x32_bf16(
                        ag[mt], v1f[nt], acc3[mt][nt], 0, 0, 0);
        }
        __syncthreads();   // h reads done before g overwrites myE
        #pragma unroll
        for (int mt = 0; mt < 2; mt++)
            #pragma unroll
            for (int nt = 0; nt < 4; nt++)
                #pragma unroll
                for (int r = 0; r < 4; r++) {
                    const int m = 4 * quad + r + 16 * mt;
                    const float gval = fmaxf(acc3[mt][nt][r] + sc1v[nfr + 16 * nt] + gv[nt], 0.0f);
                    myE[m * 72 + nfr + 16 * nt] = f2bf(gval);
                }
        __syncthreads();
        // --- V2: rgb = sigmoid(g @ V2 + c2) ---
        f32x4 acc4[2];
        acc4[0] = (f32x4){0.0f, 0.0f, 0.0f, 0.0f};
        acc4[1] = (f32x4){0.0f, 0.0f, 0.0f, 0.0f};
        {
            short8 agg[2][2];
            #pragma unroll
            for (int mt = 0; mt < 2; mt++)
                #pragma unroll
                for (int kt = 0; kt < 2; kt++)
                    agg[mt][kt] = *(const short8*)&myE[(nfr + 16 * mt) * 72 + quad * 8 + kt * 32];
            #pragma unroll
            for (int mt = 0; mt < 2; mt++)
                #pragma unroll
                for (int kt = 0; kt < 2; kt++)
                    acc4[mt] = __builtin_amdgcn_mfma_f32_16x16x32_bf16(
                        agg[mt][kt], v2f[kt], acc4[mt], 0, 0, 0);
        }
        if (nfr < 3) {
            #pragma unroll
            for (int mt = 0; mt < 2; mt++)
                #pragma unroll
                for (int r = 0; r < 4; r++) {
                    const int m = 4 * quad + r + 16 * mt;
                    const float val = acc4[mt][r] + sc2v[nfr];
                    sRgb[wave][(qq * 32 + m) * 4 + nfr] = 1.0f / (1.0f + __expf(-val));
                }
        }
    }
    __syncthreads();

    // ---- exclusive multiplicative scan + weighted reduce (per wave) ----
    const float om0 = sOm[wave][2 * lane];
    const float om1 = sOm[wave][2 * lane + 1];
    const float al0 = sAl[wave][2 * lane];
    const float al1 = sAl[wave][2 * lane + 1];

    float inc = om0 * om1;
    #pragma unroll
    for (int off = 1; off < 64; off <<= 1) {
        const float q = __shfl_up(inc, off, 64);
        if (lane >= off) inc *= q;
    }
    float Texc = __shfl_up(inc, 1, 64);
    if (lane == 0) Texc = 1.0f;

    const float T0 = Texc;
    const float T1 = Texc * om0;
    const float a0 = (T0 > 1e-4f) ? 1.0f : 0.0f;
    const float a1 = (T1 > 1e-4f) ? 1.0f : 0.0f;
    const float w0 = T0 * al0 * a0;
    const float w1 = T1 * al1 * a1;

    float cr = w0 * sRgb[wave][(2 * lane) * 4 + 0] + w1 * sRgb[wave][(2 * lane + 1) * 4 + 0];
    float cg = w0 * sRgb[wave][(2 * lane) * 4 + 1] + w1 * sRgb[wave][(2 * lane + 1) * 4 + 1];
    float cb = w0 * sRgb[wave][(2 * lane) * 4 + 2] + w1 * sRgb[wave][(2 * lane + 1) * 4 + 2];
    float tp = (a0 > 0.0f ? om0 : 1.0f) * (a1 > 0.0f ? om1 : 1.0f);

    #pragma unroll
    for (int off = 32; off > 0; off >>= 1) {
        cr += __shfl_xor(cr, off, 64);
        cg += __shfl_xor(cg, off, 64);
        cb += __shfl_xor(cb, off, 64);
        tp *= __shfl_xor(tp, off, 64);
    }

    if (lane == 0) {
        out[ray * 3 + 0] = cr;
        out[ray * 3 + 1] = cg;
        out[ray * 3 + 2] = cb;
        out[NRAYS * 3 + ray] = tp;
    }
}

extern "C" void kernel_launch(void* const* d_in, const int* in_sizes, int n_in,
                              void* d_out, int out_size, void* d_ws, size_t ws_size,
                              hipStream_t stream) {
    const float* orig = (const float*)d_in[0];
    const float* dirs = (const float*)d_in[1];
    const float* tmin = (const float*)d_in[2];
    const float* tmax = (const float*)d_in[3];
    const float* W1   = (const float*)d_in[4];
    const float* b1   = (const float*)d_in[5];
    const float* W2   = (const float*)d_in[6];
    const float* b2   = (const float*)d_in[7];
    const float* V1   = (const float*)d_in[8];
    const float* c1   = (const float*)d_in[9];
    const float* V2   = (const float*)d_in[10];
    const float* c2   = (const float*)d_in[11];
    float* dtp = (float*)d_ws;

    dt_kernel<<<1, 256, 0, stream>>>(tmin, tmax, dtp);
    march_kernel<<<NRAYS / 4, 256, 0, stream>>>(orig, dirs, tmin, tmax,
                                                W1, b1, W2, b2, V1, c1, V2, c2,
                                                dtp, (float*)d_out);
}

// Round 8
// 176.520 us; speedup vs baseline: 32.9016x; 1.1755x over previous
//
#include <hip/hip_runtime.h>
#include <hip/hip_bf16.h>

#define NRAYS 8192
#define SAMP  128
#define HID   64
#define DVD   27
#define NFEAT 15

typedef float  f32x4  __attribute__((ext_vector_type(4)));
typedef short  short8 __attribute__((ext_vector_type(8)));

// sin/cos via hardware v_sin/v_cos (REVOLUTIONS; fract reduction for domain).
static __device__ __forceinline__ float sin_fast(float x) {
    float r = x * 0.15915494309189535f;
    r = r - floorf(r);
    return __builtin_amdgcn_sinf(r);
}
static __device__ __forceinline__ float cos_fast(float x) {
    float r = x * 0.15915494309189535f;
    r = r - floorf(r);
    return __builtin_amdgcn_cosf(r);
}
// fp32 -> bf16 (RNE), raw short
static __device__ __forceinline__ short f2bf(float x) {
    unsigned u = __float_as_uint(x);
    u += 0x7FFF + ((u >> 16) & 1);
    return (short)(u >> 16);
}
static __device__ __forceinline__ float bf2f(short s) {
    return __uint_as_float(((unsigned)(unsigned short)s) << 16);
}

// ---------------------------------------------------------------------------
// Kernel 1: partial sum of (tmax - tmin) -> atomicAdd into d_ws[0]
// (d_ws[0] zeroed via hipMemsetAsync before this kernel each call)
// ---------------------------------------------------------------------------
__global__ void dt_kernel(const float* __restrict__ tmin,
                          const float* __restrict__ tmax,
                          float* __restrict__ dt_out) {
    const int i = blockIdx.x * 256 + threadIdx.x;
    float s = tmax[i] - tmin[i];
    #pragma unroll
    for (int off = 32; off > 0; off >>= 1)
        s += __shfl_xor(s, off, 64);
    if ((threadIdx.x & 63) == 0) atomicAdd(dt_out, s);
}

// ---------------------------------------------------------------------------
// Kernel 2: MFMA formulation. 1 block = 4 waves = 4 rays; per-wave LDS
// buffers -> NO per-quarter barriers (wave-lockstep + lgkmcnt ordering).
// Single __syncthreads after cooperative weight staging.
// ---------------------------------------------------------------------------
__global__ void __launch_bounds__(256)
march_kernel(const float* __restrict__ orig,
             const float* __restrict__ dirs,
             const float* __restrict__ tmin,
             const float* __restrict__ tmax,
             const float* __restrict__ W1,
             const float* __restrict__ b1,
             const float* __restrict__ W2,
             const float* __restrict__ b2,
             const float* __restrict__ V1,
             const float* __restrict__ c1,
             const float* __restrict__ V2,
             const float* __restrict__ c2,
             const float* __restrict__ dtp,
             float* __restrict__ out) {
    __shared__ __align__(16) short sW1t[64 * 72];   // W1^T [n][k], k<63 real
    __shared__ __align__(16) short sW2t[16 * 72];   // W2^T [n][k]
    __shared__ __align__(16) short sV1t[64 * 40];   // V1^T [n][k], k<15 real
    __shared__ __align__(16) short sV2t[3 * 72];    // V2^T [n][k], 3 real rows
    __shared__ float sb1v[64], sb2v[16], sc1v[64], sc2v[4];
    __shared__ float sVde[4][DVD];
    __shared__ __align__(16) short sE[4][32 * 72];  // per-wave E/h/g buffer
    __shared__ __align__(16) short sG[4][32 * 40];  // per-wave G_in buffer
    __shared__ float sOm[4][128];
    __shared__ short sRgbh[4][128 * 4];             // bf16 rgb

    const int tid  = threadIdx.x;
    const int lane = tid & 63;
    const int wave = tid >> 6;
    const int ray  = blockIdx.x * 4 + wave;

    // ---- stage weights (transposed, bf16, zero-padded) ----
    for (int i = tid; i < 64 * 72; i += 256) {
        const int n = i / 72, k = i - 72 * n;
        sW1t[i] = (k < 63) ? f2bf(W1[k * 64 + n]) : (short)0;
    }
    for (int i = tid; i < 16 * 72; i += 256) {
        const int n = i / 72, k = i - 72 * n;
        sW2t[i] = (k < 64) ? f2bf(W2[k * 16 + n]) : (short)0;
    }
    for (int i = tid; i < 64 * 40; i += 256) {
        const int n = i / 40, k = i - 40 * n;
        sV1t[i] = (k < NFEAT) ? f2bf(V1[k * 64 + n]) : (short)0;
    }
    for (int i = tid; i < 3 * 72; i += 256) {
        const int n = i / 72, k = i - 72 * n;
        sV2t[i] = (k < 64) ? f2bf(V2[k * 3 + n]) : (short)0;
    }
    for (int i = tid; i < 64; i += 256) sb1v[i] = b1[i];
    for (int i = tid; i < 16; i += 256) sb2v[i] = b2[i];
    for (int i = tid; i < 64; i += 256) sc1v[i] = c1[i];
    if (tid < 4) sc2v[tid] = (tid < 3) ? c2[tid] : 0.0f;
    for (int i = tid; i < 4 * 32 * 40; i += 256) (&sG[0][0])[i] = 0;

    // ---- per-ray scalars ----
    const float ox = orig[ray * 3 + 0];
    const float oy = orig[ray * 3 + 1];
    const float oz = orig[ray * 3 + 2];
    const float dx = dirs[ray * 3 + 0];
    const float dy = dirs[ray * 3 + 1];
    const float dz = dirs[ray * 3 + 2];
    const float t0v = tmin[ray];
    const float trange = tmax[ray] - t0v;
    const float dtv = dtp[0] * (1.0f / ((float)NRAYS * (float)SAMP));

    // ---- view-dir encoding (fp32) -> sVde (same-wave use only) ----
    {
        const float nrm = sqrtf(dx * dx + dy * dy + dz * dz);
        const float inv = 1.0f / (nrm + 1e-8f);
        const float vx = dx * inv, vy = dy * inv, vz = dz * inv;
        if (lane < DVD) {
            float val;
            if (lane < 3) {
                val = (lane == 0) ? vx : ((lane == 1) ? vy : vz);
            } else {
                const int q = lane - 3;
                const int b = q / 6;
                const int r = q - 6 * b;
                const bool isSin = (r < 3);
                const int d = isSin ? r : (r - 3);
                const float comp = (d == 0) ? vx : ((d == 1) ? vy : vz);
                const float a = (float)(1 << b) * comp;
                val = isSin ? sin_fast(a) : cos_fast(a);
            }
            sVde[wave][lane] = val;
        }
    }
    __syncthreads();   // the ONLY barrier: weights + sG zero staging (cross-wave)

    const int nfr  = lane & 15;   // n (or m) within a 16-tile
    const int quad = lane >> 4;

    // ---- hoist B-fragments into registers (once) ----
    short8 w1f[4][2], w2f[2], v1f[4], v2f[2];
    #pragma unroll
    for (int nt = 0; nt < 4; nt++)
        #pragma unroll
        for (int kt = 0; kt < 2; kt++)
            w1f[nt][kt] = *(const short8*)&sW1t[(nfr + 16 * nt) * 72 + quad * 8 + kt * 32];
    #pragma unroll
    for (int kt = 0; kt < 2; kt++)
        w2f[kt] = *(const short8*)&sW2t[nfr * 72 + quad * 8 + kt * 32];
    #pragma unroll
    for (int nt = 0; nt < 4; nt++)
        v1f[nt] = *(const short8*)&sV1t[(nfr + 16 * nt) * 40 + quad * 8];
    #pragma unroll
    for (int kt = 0; kt < 2; kt++) {
        if (nfr < 3)
            v2f[kt] = *(const short8*)&sV2t[nfr * 72 + quad * 8 + kt * 32];
        else
            v2f[kt] = (short8){0, 0, 0, 0, 0, 0, 0, 0};
    }

    // ---- gvde[n] = sum_q vde[q] * V1[15+q][n] (fp32, per ray) ----
    float gv[4] = {0.0f, 0.0f, 0.0f, 0.0f};
    #pragma unroll 1
    for (int q = 0; q < DVD; q++) {
        const float e = sVde[wave][q];
        const float* vrow = V1 + (NFEAT + q) * 64;
        #pragma unroll
        for (int nt = 0; nt < 4; nt++) gv[nt] += e * vrow[nfr + 16 * nt];
    }

    const int sl   = lane >> 1;   // local sample 0..31 (enc phase)
    const int half = lane & 1;
    short* const myE = sE[wave];
    short* const myG = sG[wave];

    #pragma unroll 1
    for (int qq = 0; qq < 4; qq++) {
        // --- positional encodings for 32 samples (2 lanes/sample) ---
        {
            const int s = qq * 32 + sl;
            const float t = t0v + (float)s * (1.0f / 127.0f) * trange;
            const float px = ox + dx * t, py = oy + dy * t, pz = oz + dz * t;
            short* Erow = &myE[sl * 72];
            if (half == 0) {
                Erow[0] = f2bf(px); Erow[1] = f2bf(py); Erow[2] = f2bf(pz);
                #pragma unroll 1
                for (int b = 0; b < 5; b++) {
                    const float f = (float)(1 << b);
                    Erow[3 + 6 * b + 0] = f2bf(sin_fast(f * px));
                    Erow[3 + 6 * b + 1] = f2bf(sin_fast(f * py));
                    Erow[3 + 6 * b + 2] = f2bf(sin_fast(f * pz));
                    Erow[3 + 6 * b + 3] = f2bf(cos_fast(f * px));
                    Erow[3 + 6 * b + 4] = f2bf(cos_fast(f * py));
                    Erow[3 + 6 * b + 5] = f2bf(cos_fast(f * pz));
                }
            } else {
                #pragma unroll 1
                for (int b = 5; b < 10; b++) {
                    const float f = (float)(1 << b);
                    Erow[3 + 6 * b + 0] = f2bf(sin_fast(f * px));
                    Erow[3 + 6 * b + 1] = f2bf(sin_fast(f * py));
                    Erow[3 + 6 * b + 2] = f2bf(sin_fast(f * pz));
                    Erow[3 + 6 * b + 3] = f2bf(cos_fast(f * px));
                    Erow[3 + 6 * b + 4] = f2bf(cos_fast(f * py));
                    Erow[3 + 6 * b + 5] = f2bf(cos_fast(f * pz));
                }
                Erow[63] = 0;
            }
        }
        // --- layer 1: h = relu(E @ W1 + b1) ---
        f32x4 acc1[2][4];
        #pragma unroll
        for (int mt = 0; mt < 2; mt++)
            #pragma unroll
            for (int nt = 0; nt < 4; nt++)
                acc1[mt][nt] = (f32x4){0.0f, 0.0f, 0.0f, 0.0f};
        {
            short8 af[2][2];
            #pragma unroll
            for (int mt = 0; mt < 2; mt++)
                #pragma unroll
                for (int kt = 0; kt < 2; kt++)
                    af[mt][kt] = *(const short8*)&myE[(nfr + 16 * mt) * 72 + quad * 8 + kt * 32];
            #pragma unroll
            for (int mt = 0; mt < 2; mt++)
                #pragma unroll
                for (int nt = 0; nt < 4; nt++)
                    #pragma unroll
                    for (int kt = 0; kt < 2; kt++)
                        acc1[mt][nt] = __builtin_amdgcn_mfma_f32_16x16x32_bf16(
                            af[mt][kt], w1f[nt][kt], acc1[mt][nt], 0, 0, 0);
        }
        #pragma unroll
        for (int mt = 0; mt < 2; mt++)
            #pragma unroll
            for (int nt = 0; nt < 4; nt++)
                #pragma unroll
                for (int r = 0; r < 4; r++) {
                    const int m = 4 * quad + r + 16 * mt;
                    const float hv = fmaxf(acc1[mt][nt][r] + sb1v[nfr + 16 * nt], 0.0f);
                    myE[m * 72 + nfr + 16 * nt] = f2bf(hv);
                }
        // --- W2: O = h @ W2 + b2 ---
        f32x4 acc2[2];
        acc2[0] = (f32x4){0.0f, 0.0f, 0.0f, 0.0f};
        acc2[1] = (f32x4){0.0f, 0.0f, 0.0f, 0.0f};
        {
            short8 ah[2][2];
            #pragma unroll
            for (int mt = 0; mt < 2; mt++)
                #pragma unroll
                for (int kt = 0; kt < 2; kt++)
                    ah[mt][kt] = *(const short8*)&myE[(nfr + 16 * mt) * 72 + quad * 8 + kt * 32];
            #pragma unroll
            for (int mt = 0; mt < 2; mt++)
                #pragma unroll
                for (int kt = 0; kt < 2; kt++)
                    acc2[mt] = __builtin_amdgcn_mfma_f32_16x16x32_bf16(
                        ah[mt][kt], w2f[kt], acc2[mt], 0, 0, 0);
        }
        if (nfr == 0) {
            #pragma unroll
            for (int mt = 0; mt < 2; mt++)
                #pragma unroll
                for (int r = 0; r < 4; r++) {
                    const int m = 4 * quad + r + 16 * mt;
                    const float sg = fmaxf(acc2[mt][r] + sb2v[0], 0.0f);
                    sOm[wave][qq * 32 + m] = __expf(-sg * dtv);
                }
        } else {
            #pragma unroll
            for (int mt = 0; mt < 2; mt++)
                #pragma unroll
                for (int r = 0; r < 4; r++) {
                    const int m = 4 * quad + r + 16 * mt;
                    myG[m * 40 + (nfr - 1)] = f2bf(acc2[mt][r] + sb2v[nfr]);
                }
        }
        // --- V1: g = relu(G_in @ V1 + c1 + gvde) ---
        f32x4 acc3[2][4];
        #pragma unroll
        for (int mt = 0; mt < 2; mt++)
            #pragma unroll
            for (int nt = 0; nt < 4; nt++)
                acc3[mt][nt] = (f32x4){0.0f, 0.0f, 0.0f, 0.0f};
        {
            short8 ag[2];
            #pragma unroll
            for (int mt = 0; mt < 2; mt++)
                ag[mt] = *(const short8*)&myG[(nfr + 16 * mt) * 40 + quad * 8];
            #pragma unroll
            for (int mt = 0; mt < 2; mt++)
                #pragma unroll
                for (int nt = 0; nt < 4; nt++)
                    acc3[mt][nt] = __builtin_amdgcn_mfma_f32_16x16x32_bf16(
                        ag[mt], v1f[nt], acc3[mt][nt], 0, 0, 0);
        }
        #pragma unroll
        for (int mt = 0; mt < 2; mt++)
            #pragma unroll
            for (int nt = 0; nt < 4; nt++)
                #pragma unroll
                for (int r = 0; r < 4; r++) {
                    const int m = 4 * quad + r + 16 * mt;
                    const float gval = fmaxf(acc3[mt][nt][r] + sc1v[nfr + 16 * nt] + gv[nt], 0.0f);
                    myE[m * 72 + nfr + 16 * nt] = f2bf(gval);
                }
        // --- V2: rgb = sigmoid(g @ V2 + c2) ---
        f32x4 acc4[2];
        acc4[0] = (f32x4){0.0f, 0.0f, 0.0f, 0.0f};
        acc4[1] = (f32x4){0.0f, 0.0f, 0.0f, 0.0f};
        {
            short8 agg[2][2];
            #pragma unroll
            for (int mt = 0; mt < 2; mt++)
                #pragma unroll
                for (int kt = 0; kt < 2; kt++)
                    agg[mt][kt] = *(const short8*)&myE[(nfr + 16 * mt) * 72 + quad * 8 + kt * 32];
            #pragma unroll
            for (int mt = 0; mt < 2; mt++)
                #pragma unroll
                for (int kt = 0; kt < 2; kt++)
                    acc4[mt] = __builtin_amdgcn_mfma_f32_16x16x32_bf16(
                        agg[mt][kt], v2f[kt], acc4[mt], 0, 0, 0);
        }
        if (nfr < 3) {
            #pragma unroll
            for (int mt = 0; mt < 2; mt++)
                #pragma unroll
                for (int r = 0; r < 4; r++) {
                    const int m = 4 * quad + r + 16 * mt;
                    const float val = acc4[mt][r] + sc2v[nfr];
                    sRgbh[wave][(qq * 32 + m) * 4 + nfr] = f2bf(1.0f / (1.0f + __expf(-val)));
                }
        }
    }

    // ---- exclusive multiplicative scan + weighted reduce (per wave) ----
    const float om0 = sOm[wave][2 * lane];
    const float om1 = sOm[wave][2 * lane + 1];
    const float al0 = 1.0f - om0;
    const float al1 = 1.0f - om1;

    float inc = om0 * om1;
    #pragma unroll
    for (int off = 1; off < 64; off <<= 1) {
        const float q = __shfl_up(inc, off, 64);
        if (lane >= off) inc *= q;
    }
    float Texc = __shfl_up(inc, 1, 64);
    if (lane == 0) Texc = 1.0f;

    const float T0 = Texc;
    const float T1 = Texc * om0;
    const float a0 = (T0 > 1e-4f) ? 1.0f : 0.0f;
    const float a1 = (T1 > 1e-4f) ? 1.0f : 0.0f;
    const float w0 = T0 * al0 * a0;
    const float w1 = T1 * al1 * a1;

    float cr = w0 * bf2f(sRgbh[wave][(2 * lane) * 4 + 0]) + w1 * bf2f(sRgbh[wave][(2 * lane + 1) * 4 + 0]);
    float cg = w0 * bf2f(sRgbh[wave][(2 * lane) * 4 + 1]) + w1 * bf2f(sRgbh[wave][(2 * lane + 1) * 4 + 1]);
    float cb = w0 * bf2f(sRgbh[wave][(2 * lane) * 4 + 2]) + w1 * bf2f(sRgbh[wave][(2 * lane + 1) * 4 + 2]);
    float tp = (a0 > 0.0f ? om0 : 1.0f) * (a1 > 0.0f ? om1 : 1.0f);

    #pragma unroll
    for (int off = 32; off > 0; off >>= 1) {
        cr += __shfl_xor(cr, off, 64);
        cg += __shfl_xor(cg, off, 64);
        cb += __shfl_xor(cb, off, 64);
        tp *= __shfl_xor(tp, off, 64);
    }

    if (lane == 0) {
        out[ray * 3 + 0] = cr;
        out[ray * 3 + 1] = cg;
        out[ray * 3 + 2] = cb;
        out[NRAYS * 3 + ray] = tp;
    }
}

extern "C" void kernel_launch(void* const* d_in, const int* in_sizes, int n_in,
                              void* d_out, int out_size, void* d_ws, size_t ws_size,
                              hipStream_t stream) {
    const float* orig = (const float*)d_in[0];
    const float* dirs = (const float*)d_in[1];
    const float* tmin = (const float*)d_in[2];
    const float* tmax = (const float*)d_in[3];
    const float* W1   = (const float*)d_in[4];
    const float* b1   = (const float*)d_in[5];
    const float* W2   = (const float*)d_in[6];
    const float* b2   = (const float*)d_in[7];
    const float* V1   = (const float*)d_in[8];
    const float* c1   = (const float*)d_in[9];
    const float* V2   = (const float*)d_in[10];
    const float* c2   = (const float*)d_in[11];
    float* dtp = (float*)d_ws;

    hipMemsetAsync(dtp, 0, sizeof(float), stream);
    dt_kernel<<<NRAYS / 256, 256, 0, stream>>>(tmin, tmax, dtp);
    march_kernel<<<NRAYS / 4, 256, 0, stream>>>(orig, dirs, tmin, tmax,
                                                W1, b1, W2, b2, V1, c1, V2, c2,
                                                dtp, (float*)d_out);
}